// Round 20
// baseline (44.302 us; speedup 1.0000x reference)
//
#include <hip/hip_runtime.h>
#include <math.h>

#define N      8192
#define BLK    256
#define RPT    8                    // resident b-points per lane
#define G      (RPT / 2)            // packed pair-groups per lane
#define BPW    (64 * RPT)           // 512 b-points per wave
#define NB     (N / BPW)            // 16 b-groups
#define NA     (N / 64)             // 128 a-tiles
#define NW     (NB * NA)            // 2048 waves
#define GRID   (NW / 4)             // 512 blocks of 4 waves
#define CBLK   256
#define CGRID  (2 * N / CBLK)       // 64 combine blocks (0-31 rows, 32-63 cols)

typedef float v2f __attribute__((ext_vector_type(2)));

// Full-wave rotate-by-1 on the VALU pipe (DPP wave_ror:1, ctrl 0x13C).
__device__ __forceinline__ float rot1(float x) {
    return __int_as_float(__builtin_amdgcn_mov_dpp(
        __float_as_int(x), 0x13C, 0xF, 0xF, false));
}

// ------------------------------------------------------------------ prep ----
// P[0..N) = target {x,y,z,|p|^2}; P[N..2N) = output.
__global__ __launch_bounds__(BLK) void chamfer_prep_kernel(
        const float* __restrict__ tgt, const float* __restrict__ outp,
        float4* __restrict__ P) {
    int i = blockIdx.x * BLK + (int)threadIdx.x;   // 0 .. 2N-1
    const float* src = (i < N) ? tgt : outp;
    int k = (i < N) ? i : (i - N);
    float x = src[3 * k + 0];
    float y = src[3 * k + 1];
    float z = src[3 * k + 2];
    P[i] = make_float4(x, y, z, fmaf(x, x, fmaf(y, y, z * z)));
}

// ------------------------------------------------------------------ dist ----
// R18 DPP systolic ring (best: 23.98us), with the commit tail REPLACED:
// R19's sweep-scaling probe isolated a ~12.7us sweep-independent fixed cost
// == the ~1.18M device-scope atomicMin burst (each dist2 word took ~128
// serialized cross-XCD RMWs). Now each wave stores PRIVATE partials with
// plain coalesced stores (zero atomics): rowp[bt][a-point], colp[W][slot].
// Kernel-boundary ordering makes them visible to the combine kernel.
__global__ __launch_bounds__(BLK) void chamfer_dist_kernel(
        const float4* __restrict__ P,
        float* __restrict__ rowp,        // [NB][N]   row-min partials (d^2)
        float* __restrict__ colp) {      // [NW][BPW] col-min partials (d^2)
    int tid  = (int)threadIdx.x;
    int lane = tid & 63;
    int W    = (int)blockIdx.x * 4 + (tid >> 6);   // global wave id
    int bt   = W % NB;                             // b-group
    int at   = W / NB;                             // a-tile

    // resident B-points (output cloud), packed as point-pairs
    v2f bx2[G], by2[G], bz2[G], b22[G], ca2[G];
    #pragma unroll
    for (int g = 0; g < G; ++g) {
        float4 u = P[N + bt * BPW + (2 * g)     * 64 + lane];
        float4 v = P[N + bt * BPW + (2 * g + 1) * 64 + lane];
        bx2[g] = (v2f){u.x, v.x};
        by2[g] = (v2f){u.y, v.y};
        bz2[g] = (v2f){u.z, v.z};
        b22[g] = (v2f){u.w, v.w};
        ca2[g] = (v2f){__builtin_inff(), __builtin_inff()};
    }

    // own A-packet (target cloud)
    float4 a = P[at * 64 + lane];
    float px = -2.0f * a.x;
    float py = -2.0f * a.y;
    float pz = -2.0f * a.z;
    float pw = a.w;                       // a^2
    float pr = __builtin_inff();          // traveling row-min (d^2)

    for (int s = 0; s < 64; ++s) {
        v2f px2 = {px, px}, py2 = {py, py}, pz2 = {pz, pz}, pw2 = {pw, pw};
        #pragma unroll
        for (int g = 0; g < G; ++g) {
            v2f t = __builtin_elementwise_fma(pz2, bz2[g], b22[g] + pw2);
            t     = __builtin_elementwise_fma(py2, by2[g], t);
            t     = __builtin_elementwise_fma(px2, bx2[g], t);   // full d^2
            pr     = fminf(fminf(pr, t.x), t.y);                 // v_min3
            ca2[g] = __builtin_elementwise_min(ca2[g], t);
        }
        px = rot1(px);
        py = rot1(py);
        pz = rot1(pz);
        pw = rot1(pw);
        pr = rot1(pr);
    }

    // packet is home: plain coalesced partial stores, ZERO atomics
    rowp[bt * N + at * 64 + lane] = pr;
    float* cp = colp + (size_t)W * BPW;
    #pragma unroll
    for (int g = 0; g < G; ++g) {
        cp[(2 * g)     * 64 + lane] = ca2[g].x;
        cp[(2 * g + 1) * 64 + lane] = ca2[g].y;
    }
}

// --------------------------------------------------------------- combine ----
// One thread per point (16384 total). a-point i: min over NB=16 row partials
// (coalesced, independent loads). b-point (bt,slot): min over NA=128 col
// partials at stride NB*BPW (lane-consecutive slots -> coalesced). Then
// sqrt, wave+block sum, one partial per block. No atomics.
__global__ __launch_bounds__(CBLK) void chamfer_combine_kernel(
        const float* __restrict__ rowp, const float* __restrict__ colp,
        float* __restrict__ bsum) {
    __shared__ float sh[CBLK / 64];
    int t = (int)blockIdx.x * CBLK + (int)threadIdx.x;   // 0 .. 16383
    float m = __builtin_inff();
    if (t < N) {                       // dist1: a-point i = t
        #pragma unroll
        for (int bt = 0; bt < NB; ++bt)
            m = fminf(m, rowp[bt * N + t]);
    } else {                           // dist2: b-point j = t - N
        int j = t - N;
        int bt = j >> 9;               // j / BPW
        int slot = j & (BPW - 1);
        const float* cp = colp + (size_t)bt * BPW + slot;
        #pragma unroll 8
        for (int at = 0; at < NA; ++at)
            m = fminf(m, cp[(size_t)at * NB * BPW]);
    }
    float s = sqrtf(fmaxf(m, 0.0f));
    #pragma unroll
    for (int off = 32; off > 0; off >>= 1) s += __shfl_down(s, off, 64);
    int wid = (int)threadIdx.x >> 6, lane = (int)threadIdx.x & 63;
    if (lane == 0) sh[wid] = s;
    __syncthreads();
    if (threadIdx.x == 0) {
        float b = 0.0f;
        #pragma unroll
        for (int w = 0; w < CBLK / 64; ++w) b += sh[w];
        bsum[blockIdx.x] = b;
    }
}

// ----------------------------------------------------------------- final ----
__global__ void chamfer_final_kernel(const float* __restrict__ bsum,
        const int* __restrict__ curp, const int* __restrict__ subp,
        float* __restrict__ out) {
    if (threadIdx.x != 0) return;
    float s1 = 0.0f, s2 = 0.0f;
    for (int b = 0; b < CGRID / 2; ++b)     s1 += bsum[b];
    for (int b = CGRID / 2; b < CGRID; ++b) s2 += bsum[b];
    int e = curp[0] / subp[0];
    double scale = 10.0 / pow(0.99, (double)e);
    out[0] = (float)((((double)s1 + (double)s2) / (double)N) * 0.5 * scale);
}

// ---------------------------------------------------------------- launch ----
extern "C" void kernel_launch(void* const* d_in, const int* in_sizes, int n_in,
                              void* d_out, int out_size, void* d_ws, size_t ws_size,
                              hipStream_t stream) {
    const float* target = (const float*)d_in[0];   // (1, 8192, 3) f32
    const float* output = (const float*)d_in[1];   // (1, 8192, 3) f32
    const int*   curp   = (const int*)d_in[2];
    const int*   subp   = (const int*)d_in[3];
    float* out = (float*)d_out;

    // ws: P float4[2N] (256KB) | rowp [NB*N] (512KB) | colp [NW*BPW] (4MB)
    //     | bsum [CGRID]
    float4* P    = (float4*)d_ws;
    float*  rowp = (float*)(P + 2 * N);
    float*  colp = rowp + NB * N;
    float*  bsum = colp + (size_t)NW * BPW;

    chamfer_prep_kernel<<<2 * N / BLK, BLK, 0, stream>>>(target, output, P);
    chamfer_dist_kernel<<<GRID, BLK, 0, stream>>>(P, rowp, colp);
    chamfer_combine_kernel<<<CGRID, CBLK, 0, stream>>>(rowp, colp, bsum);
    chamfer_final_kernel<<<1, 64, 0, stream>>>(bsum, curp, subp, out);
}

// Round 21
// 22.940 us; speedup vs baseline: 1.9312x; 1.9312x over previous
//
#include <hip/hip_runtime.h>
#include <math.h>

#define N      8192
#define BLK    256
#define RPT    8                    // resident b-points per lane
#define G      (RPT / 2)            // packed pair-groups per lane
#define BPW    (64 * RPT)           // 512 b-points per wave
#define NB     (N / BPW)            // 16 b-groups
#define NA     (N / 64)             // 128 a-tiles
#define GRID   ((NB * NA) / 4)      // 512 blocks of 4 waves
#define RBLK   1024

typedef float v2f __attribute__((ext_vector_type(2)));

// Full-wave rotate-by-1 on the VALU pipe (DPP wave_ror:1, ctrl 0x13C).
__device__ __forceinline__ float rot1(float x) {
    return __int_as_float(__builtin_amdgcn_mov_dpp(
        __float_as_int(x), 0x13C, 0xF, 0xF, false));
}

// ---------------------------------------------------- precompute + init ----
// P[0..N) = target {x,y,z,|p|^2}; P[N..2N) = output. dmin = +inf bits.
__global__ __launch_bounds__(BLK) void chamfer_prep_kernel(
        const float* __restrict__ tgt, const float* __restrict__ outp,
        float4* __restrict__ P, unsigned* __restrict__ dmin) {
    int i = blockIdx.x * BLK + (int)threadIdx.x;   // 0 .. 2N-1
    const float* src = (i < N) ? tgt : outp;
    int k = (i < N) ? i : (i - N);
    float x = src[3 * k + 0];
    float y = src[3 * k + 1];
    float z = src[3 * k + 2];
    P[i] = make_float4(x, y, z, fmaf(x, x, fmaf(y, y, z * z)));
    dmin[i] = 0x7F800000u;  // +inf
}

// ---------------------------------------------------------------- dist ----
// R18 DPP systolic ring (best: 23.98us) with ONE change: the block's 4
// waves now share the SAME b-group (bt = W>>7), so their col-mins cover
// identical 512 b-points -> pre-combine in LDS (cheap LDS-pipe atomics)
// and commit ONCE per block. Device-scope atomics: 1.18M -> 393K (3x).
// R20 taught: partials must be combined while resident (same kernel, LDS),
// not via a second kernel (cross-kernel L2 invalidate made that lose).
__global__ __launch_bounds__(BLK) void chamfer_dist_kernel(
        const float4* __restrict__ P, unsigned* __restrict__ dmin) {
    __shared__ unsigned cm[BPW];               // block-combined col-mins

    int tid  = (int)threadIdx.x;
    int lane = tid & 63;
    int W    = (int)blockIdx.x * 4 + (tid >> 6);   // global wave id
    int bt   = W >> 7;                             // b-group (shared by block)
    int at   = W & (NA - 1);                       // a-tile  (per wave)

    cm[tid]       = 0x7F800000u;
    cm[tid + 256] = 0x7F800000u;

    // resident B-points (output cloud), packed as point-pairs
    v2f bx2[G], by2[G], bz2[G], b22[G], ca2[G];
    #pragma unroll
    for (int g = 0; g < G; ++g) {
        float4 u = P[N + bt * BPW + (2 * g)     * 64 + lane];
        float4 v = P[N + bt * BPW + (2 * g + 1) * 64 + lane];
        bx2[g] = (v2f){u.x, v.x};
        by2[g] = (v2f){u.y, v.y};
        bz2[g] = (v2f){u.z, v.z};
        b22[g] = (v2f){u.w, v.w};
        ca2[g] = (v2f){__builtin_inff(), __builtin_inff()};
    }

    // own A-packet (target cloud)
    float4 a = P[at * 64 + lane];
    float px = -2.0f * a.x;
    float py = -2.0f * a.y;
    float pz = -2.0f * a.z;
    float pw = a.w;                       // a^2
    float pr = __builtin_inff();          // traveling row-min (d^2)

    __syncthreads();                      // cm initialized

    for (int s = 0; s < 64; ++s) {
        v2f px2 = {px, px}, py2 = {py, py}, pz2 = {pz, pz}, pw2 = {pw, pw};
        #pragma unroll
        for (int g = 0; g < G; ++g) {
            v2f t = __builtin_elementwise_fma(pz2, bz2[g], b22[g] + pw2);
            t     = __builtin_elementwise_fma(py2, by2[g], t);
            t     = __builtin_elementwise_fma(px2, bx2[g], t);   // full d^2
            pr     = fminf(fminf(pr, t.x), t.y);                 // v_min3
            ca2[g] = __builtin_elementwise_min(ca2[g], t);
        }
        px = rot1(px);
        py = rot1(py);
        pz = rot1(pz);
        pw = rot1(pw);
        pr = rot1(pr);
    }

    // packet is home: commit row-min (per-wave a-tile, unchanged)
    atomicMin(&dmin[at * 64 + lane], __float_as_uint(fmaxf(pr, 0.0f)));

    // col-mins: LDS pre-combine across the block's 4 waves, then ONE
    // global commit per b-point per block (262K total vs 1.05M).
    #pragma unroll
    for (int g = 0; g < G; ++g) {
        atomicMin(&cm[(2 * g)     * 64 + lane],
                  __float_as_uint(fmaxf(ca2[g].x, 0.0f)));
        atomicMin(&cm[(2 * g + 1) * 64 + lane],
                  __float_as_uint(fmaxf(ca2[g].y, 0.0f)));
    }
    __syncthreads();
    atomicMin(&dmin[N + bt * BPW + tid],       cm[tid]);
    atomicMin(&dmin[N + bt * BPW + tid + 256], cm[tid + 256]);
}

// -------------------------------------------------------------- reduce ----
__global__ __launch_bounds__(RBLK) void chamfer_reduce_kernel(
        const unsigned* __restrict__ dmin,
        const int* __restrict__ curp, const int* __restrict__ subp,
        float* __restrict__ out) {
    __shared__ float sh1[RBLK / 64], sh2[RBLK / 64];
    int t = (int)threadIdx.x;
    float s1 = 0.0f, s2 = 0.0f;
    const uint4* da = (const uint4*)dmin;          // dist1 as uint4
    const uint4* db = (const uint4*)(dmin + N);    // dist2 as uint4
    for (int i = t; i < N / 4; i += RBLK) {
        uint4 v1 = da[i], v2 = db[i];
        s1 += sqrtf(__uint_as_float(v1.x)) + sqrtf(__uint_as_float(v1.y))
            + sqrtf(__uint_as_float(v1.z)) + sqrtf(__uint_as_float(v1.w));
        s2 += sqrtf(__uint_as_float(v2.x)) + sqrtf(__uint_as_float(v2.y))
            + sqrtf(__uint_as_float(v2.z)) + sqrtf(__uint_as_float(v2.w));
    }
    #pragma unroll
    for (int off = 32; off > 0; off >>= 1) {
        s1 += __shfl_down(s1, off, 64);
        s2 += __shfl_down(s2, off, 64);
    }
    int wid = t >> 6, lane = t & 63;
    if (lane == 0) { sh1[wid] = s1; sh2[wid] = s2; }
    __syncthreads();
    if (t == 0) {
        float t1 = 0.0f, t2 = 0.0f;
        #pragma unroll
        for (int w = 0; w < RBLK / 64; ++w) { t1 += sh1[w]; t2 += sh2[w]; }
        int e = curp[0] / subp[0];
        double scale = 10.0 / pow(0.99, (double)e);
        out[0] = (float)((((double)t1 + (double)t2) / (double)N) * 0.5 * scale);
    }
}

// ---------------------------------------------------------------- launch ----
extern "C" void kernel_launch(void* const* d_in, const int* in_sizes, int n_in,
                              void* d_out, int out_size, void* d_ws, size_t ws_size,
                              hipStream_t stream) {
    const float* target = (const float*)d_in[0];   // (1, 8192, 3) f32
    const float* output = (const float*)d_in[1];   // (1, 8192, 3) f32
    const int*   curp   = (const int*)d_in[2];
    const int*   subp   = (const int*)d_in[3];
    float* out = (float*)d_out;

    // ws: float4 P[2N] (256KB) | uint dmin[2N] (64KB)
    float4*   P    = (float4*)d_ws;
    unsigned* dmin = (unsigned*)(P + 2 * N);

    chamfer_prep_kernel<<<2 * N / BLK, BLK, 0, stream>>>(target, output, P, dmin);
    chamfer_dist_kernel<<<GRID, BLK, 0, stream>>>(P, dmin);
    chamfer_reduce_kernel<<<1, RBLK, 0, stream>>>(dmin, curp, subp, out);
}

// Round 22
// 22.727 us; speedup vs baseline: 1.9493x; 1.0094x over previous
//
#include <hip/hip_runtime.h>
#include <math.h>

#define N      8192
#define BLK    256
#define RPT    8                    // resident b-points per lane
#define G      (RPT / 2)            // packed pair-groups per lane
#define BPW    (64 * RPT)           // 512 b-points per wave
#define NB     (N / BPW)            // 16 b-groups
#define NA     (N / 64)             // 128 a-tiles
#define GRID   ((NB * NA) / 4)      // 512 blocks of 4 waves
#define RBLK   1024
#define RGRID  8                    // widened reduce: 8 blocks

typedef float v2f __attribute__((ext_vector_type(2)));

// Full-wave rotate-by-1 on the VALU pipe (DPP wave_ror:1, ctrl 0x13C).
__device__ __forceinline__ float rot1(float x) {
    return __int_as_float(__builtin_amdgcn_mov_dpp(
        __float_as_int(x), 0x13C, 0xF, 0xF, false));
}

// ---------------------------------------------------- precompute + init ----
__global__ __launch_bounds__(BLK) void chamfer_prep_kernel(
        const float* __restrict__ tgt, const float* __restrict__ outp,
        float4* __restrict__ P, unsigned* __restrict__ dmin) {
    int i = blockIdx.x * BLK + (int)threadIdx.x;   // 0 .. 2N-1
    const float* src = (i < N) ? tgt : outp;
    int k = (i < N) ? i : (i - N);
    float x = src[3 * k + 0];
    float y = src[3 * k + 1];
    float z = src[3 * k + 2];
    P[i] = make_float4(x, y, z, fmaf(x, x, fmaf(y, y, z * z)));
    dmin[i] = 0x7F800000u;  // +inf
}

// ---------------------------------------------------------------- dist ----
// R21 structure (best: 22.94us) with the rotation SOFTWARE-PIPELINED:
// 2x-unrolled p/q ping-pong. The 4 position rotations issue at the TOP of
// each half-body (operands last written ~25 inst earlier -> no VALU->DPP
// hazard bubble); only rot1(pr) remains hazard-adjacent (5 -> 1 hazard
// point per step, unhidden at 2 waves/SIMD).
#define STEP(PX, PY, PZ, PW)                                              \
    {                                                                     \
        v2f px2 = {PX, PX}, py2 = {PY, PY}, pz2 = {PZ, PZ}, pw2 = {PW, PW}; \
        _Pragma("unroll")                                                 \
        for (int g = 0; g < G; ++g) {                                     \
            v2f t = __builtin_elementwise_fma(pz2, bz2[g], b22[g] + pw2); \
            t     = __builtin_elementwise_fma(py2, by2[g], t);            \
            t     = __builtin_elementwise_fma(px2, bx2[g], t);            \
            pr     = fminf(fminf(pr, t.x), t.y);                          \
            ca2[g] = __builtin_elementwise_min(ca2[g], t);                \
        }                                                                 \
        pr = rot1(pr);                                                    \
    }

__global__ __launch_bounds__(BLK) void chamfer_dist_kernel(
        const float4* __restrict__ P, unsigned* __restrict__ dmin) {
    __shared__ unsigned cm[BPW];               // block-combined col-mins

    int tid  = (int)threadIdx.x;
    int lane = tid & 63;
    int W    = (int)blockIdx.x * 4 + (tid >> 6);   // global wave id
    int bt   = W >> 7;                             // b-group (shared by block)
    int at   = W & (NA - 1);                       // a-tile  (per wave)

    cm[tid]       = 0x7F800000u;
    cm[tid + 256] = 0x7F800000u;

    // resident B-points (output cloud), packed as point-pairs
    v2f bx2[G], by2[G], bz2[G], b22[G], ca2[G];
    #pragma unroll
    for (int g = 0; g < G; ++g) {
        float4 u = P[N + bt * BPW + (2 * g)     * 64 + lane];
        float4 v = P[N + bt * BPW + (2 * g + 1) * 64 + lane];
        bx2[g] = (v2f){u.x, v.x};
        by2[g] = (v2f){u.y, v.y};
        bz2[g] = (v2f){u.z, v.z};
        b22[g] = (v2f){u.w, v.w};
        ca2[g] = (v2f){__builtin_inff(), __builtin_inff()};
    }

    // own A-packet (target cloud)
    float4 a = P[at * 64 + lane];
    float px = -2.0f * a.x;
    float py = -2.0f * a.y;
    float pz = -2.0f * a.z;
    float pw = a.w;                       // a^2
    float pr = __builtin_inff();          // traveling row-min (d^2)
    float qx, qy, qz, qw;

    __syncthreads();                      // cm initialized

    #pragma unroll 4
    for (int s = 0; s < 64; s += 2) {
        // half A: early-rotate positions into q (no hazard), compute with p
        qx = rot1(px); qy = rot1(py); qz = rot1(pz); qw = rot1(pw);
        STEP(px, py, pz, pw)
        // half B: early-rotate q back into p (for step s+2), compute with q
        px = rot1(qx); py = rot1(qy); pz = rot1(qz); pw = rot1(qw);
        STEP(qx, qy, qz, qw)
    }

    // packet home after 64 rotations: commit row-min (per-wave a-tile)
    atomicMin(&dmin[at * 64 + lane], __float_as_uint(fmaxf(pr, 0.0f)));

    // col-mins: LDS pre-combine across the block's 4 waves, then ONE
    // global commit per b-point per block.
    #pragma unroll
    for (int g = 0; g < G; ++g) {
        atomicMin(&cm[(2 * g)     * 64 + lane],
                  __float_as_uint(fmaxf(ca2[g].x, 0.0f)));
        atomicMin(&cm[(2 * g + 1) * 64 + lane],
                  __float_as_uint(fmaxf(ca2[g].y, 0.0f)));
    }
    __syncthreads();
    atomicMin(&dmin[N + bt * BPW + tid],       cm[tid]);
    atomicMin(&dmin[N + bt * BPW + tid + 256], cm[tid + 256]);
}

// -------------------------------------------------------------- reduce ----
// Widened: 8 blocks x 1024 threads (64 waves total, 8 CUs), each covering
// 1/8 of both dmin arrays; per-block partials to bsum[2][RGRID].
__global__ __launch_bounds__(RBLK) void chamfer_reduce_kernel(
        const unsigned* __restrict__ dmin, float* __restrict__ bsum) {
    __shared__ float sh1[RBLK / 64], sh2[RBLK / 64];
    int t = (int)threadIdx.x;
    int chunk = N / 4 / RGRID;                     // uint4 elems per block
    int base = (int)blockIdx.x * chunk;
    float s1 = 0.0f, s2 = 0.0f;
    const uint4* da = (const uint4*)dmin;          // dist1 as uint4
    const uint4* db = (const uint4*)(dmin + N);    // dist2 as uint4
    for (int i = t; i < chunk; i += RBLK) {
        uint4 v1 = da[base + i], v2 = db[base + i];
        s1 += sqrtf(__uint_as_float(v1.x)) + sqrtf(__uint_as_float(v1.y))
            + sqrtf(__uint_as_float(v1.z)) + sqrtf(__uint_as_float(v1.w));
        s2 += sqrtf(__uint_as_float(v2.x)) + sqrtf(__uint_as_float(v2.y))
            + sqrtf(__uint_as_float(v2.z)) + sqrtf(__uint_as_float(v2.w));
    }
    #pragma unroll
    for (int off = 32; off > 0; off >>= 1) {
        s1 += __shfl_down(s1, off, 64);
        s2 += __shfl_down(s2, off, 64);
    }
    int wid = t >> 6, lane = t & 63;
    if (lane == 0) { sh1[wid] = s1; sh2[wid] = s2; }
    __syncthreads();
    if (t == 0) {
        float t1 = 0.0f, t2 = 0.0f;
        #pragma unroll
        for (int w = 0; w < RBLK / 64; ++w) { t1 += sh1[w]; t2 += sh2[w]; }
        bsum[blockIdx.x]         = t1;
        bsum[RGRID + blockIdx.x] = t2;
    }
}

// ----------------------------------------------------------------- final ----
__global__ void chamfer_final_kernel(const float* __restrict__ bsum,
        const int* __restrict__ curp, const int* __restrict__ subp,
        float* __restrict__ out) {
    if (threadIdx.x != 0) return;
    float s1 = 0.0f, s2 = 0.0f;
    #pragma unroll
    for (int b = 0; b < RGRID; ++b) { s1 += bsum[b]; s2 += bsum[RGRID + b]; }
    int e = curp[0] / subp[0];
    double scale = 10.0 / pow(0.99, (double)e);
    out[0] = (float)((((double)s1 + (double)s2) / (double)N) * 0.5 * scale);
}

// ---------------------------------------------------------------- launch ----
extern "C" void kernel_launch(void* const* d_in, const int* in_sizes, int n_in,
                              void* d_out, int out_size, void* d_ws, size_t ws_size,
                              hipStream_t stream) {
    const float* target = (const float*)d_in[0];   // (1, 8192, 3) f32
    const float* output = (const float*)d_in[1];   // (1, 8192, 3) f32
    const int*   curp   = (const int*)d_in[2];
    const int*   subp   = (const int*)d_in[3];
    float* out = (float*)d_out;

    // ws: float4 P[2N] (256KB) | uint dmin[2N] (64KB) | float bsum[16]
    float4*   P    = (float4*)d_ws;
    unsigned* dmin = (unsigned*)(P + 2 * N);
    float*    bsum = (float*)(dmin + 2 * N);

    chamfer_prep_kernel<<<2 * N / BLK, BLK, 0, stream>>>(target, output, P, dmin);
    chamfer_dist_kernel<<<GRID, BLK, 0, stream>>>(P, dmin);
    chamfer_reduce_kernel<<<RGRID, RBLK, 0, stream>>>(dmin, bsum);
    chamfer_final_kernel<<<1, 64, 0, stream>>>(bsum, curp, subp, out);
}